// Round 3
// baseline (397.604 us; speedup 1.0000x reference)
//
#include <hip/hip_runtime.h>

constexpr int NN = 100000;   // nodes
constexpr int DI = 256;      // in features
constexpr int DO = 128;      // out features
constexpr int NE = 1600000;  // edges

constexpr int BROWS = 128;                        // rows per bucket
constexpr int NBK   = (NN + BROWS - 1) / BROWS;   // 782 buckets
constexpr int TILE  = 8192;                       // edges per partition block
constexpr int CAP   = 2688;                       // slots per bucket (mean 2046, sd ~45)

typedef __bf16 bf16x8 __attribute__((ext_vector_type(8)));
typedef float  f32x4  __attribute__((ext_vector_type(4)));

__device__ inline unsigned short f2bf(float f) {
    union { float f; unsigned u; } v; v.f = f;
    return (unsigned short)((v.u + 0x7FFF + ((v.u >> 16) & 1)) >> 16);
}
__device__ inline float bf2f(unsigned u16) {
    union { unsigned u; float f; } v; v.u = u16 << 16;
    return v.f;
}

// ---------------- W transpose: W[256][128] f32 -> Wt[128][256] bf16 ----------
__global__ __launch_bounds__(256)
void wt_kernel(const float* __restrict__ W, unsigned short* __restrict__ Wt) {
    __shared__ float t[32][33];
    const int tx = threadIdx.x & 31, ty = threadIdx.x >> 5;
    const int k0 = (blockIdx.x >> 2) * 32, n0 = (blockIdx.x & 3) * 32;
#pragma unroll
    for (int i = 0; i < 32; i += 8)
        t[ty + i][tx] = W[(size_t)(k0 + ty + i) * DO + n0 + tx];
    __syncthreads();
#pragma unroll
    for (int i = 0; i < 32; i += 8)
        Wt[(size_t)(n0 + ty + i) * DI + k0 + tx] = f2bf(t[tx][ty + i]);
}

// ---------------- GEMM: h = bf16( (x*mask) @ W ), barrier-free MFMA ---------
// Each wave owns 16 output rows x all 128 cols. A fragments (row = l15,
// k = l4*8 + ks*32) are loaded DIRECTLY from global into registers (two
// float4 per fragment, 128B-per-row segments, L3-resident). B fragments come
// straight from Wt (64 KB, L1/L2-hot; per-step working set 16 KB shared by
// the co-resident waves). No LDS, no __syncthreads => no s_waitcnt vmcnt(0)
// barrier drains; the compiler pipelines loads of step s+1 across the MFMAs
// of step s. Old version: 2 barriers/K-step serialized every load batch ->
// 1.4 TB/s, MfmaUtil 2.6%, 92 us.
union BF8 { bf16x8 v; unsigned short u[8]; };

__device__ inline bf16x8 mk8(const float4& a, const float4& b,
                             const float4& ma, const float4& mb) {
    BF8 r;
    r.u[0] = f2bf(a.x * ma.x); r.u[1] = f2bf(a.y * ma.y);
    r.u[2] = f2bf(a.z * ma.z); r.u[3] = f2bf(a.w * ma.w);
    r.u[4] = f2bf(b.x * mb.x); r.u[5] = f2bf(b.y * mb.y);
    r.u[6] = f2bf(b.z * mb.z); r.u[7] = f2bf(b.w * mb.w);
    return r.v;
}

__global__ __launch_bounds__(256)
void gemm_kernel(const float* __restrict__ x, const float* __restrict__ mask,
                 const unsigned short* __restrict__ Wt,
                 unsigned short* __restrict__ h) {
    const int tid  = threadIdx.x;
    const int lane = tid & 63;
    const int w    = tid >> 6;          // wave 0..3
    const int m0   = blockIdx.x * 64;
    const int mw   = w * 16;            // wave's 16-row slice
    const int l15  = lane & 15;
    const int l4   = lane >> 4;

    // this lane's A row (clamped for the grid tail; stores are guarded)
    const int arow = m0 + mw + l15;
    const size_t rbase = (size_t)(arow < NN ? arow : 0) * DI + l4 * 8;
    const float4* xp = (const float4*)(x + rbase);     // float4 index i = 4*i floats
    const float4* mp = (const float4*)(mask + rbase);

    f32x4 acc[8];
#pragma unroll
    for (int ct = 0; ct < 8; ++ct) acc[ct] = (f32x4){0.f, 0.f, 0.f, 0.f};

    // A data for one K-step: ks=0 pair, ks=1 pair (x and mask)
    float4 xr[4], mr[4];
    // float4 index of fragment (kc, ks): kc/4 + ks*8 (+1 for second half)
#define LOADA(S)                                                   \
    do {                                                           \
        const int o = (S) * 16; /* kc/4 = S*64/4 */                \
        xr[0] = xp[o + 0]; xr[1] = xp[o + 1];                      \
        xr[2] = xp[o + 8]; xr[3] = xp[o + 9];                      \
        mr[0] = mp[o + 0]; mr[1] = mp[o + 1];                      \
        mr[2] = mp[o + 8]; mr[3] = mp[o + 9];                      \
    } while (0)

    LOADA(0);
#pragma unroll
    for (int s = 0; s < 4; ++s) {
        const int kc = s * 64;
        const bf16x8 a0 = mk8(xr[0], xr[1], mr[0], mr[1]);   // ks=0
        const bf16x8 a1 = mk8(xr[2], xr[3], mr[2], mr[3]);   // ks=1
        if (s < 3) LOADA(s + 1);   // next-step A loads overlap MFMAs below
#pragma unroll
        for (int ct = 0; ct < 8; ++ct) {
            const unsigned short* bp =
                Wt + (size_t)(ct * 16 + l15) * DI + kc + l4 * 8;
            const bf16x8 b0 = *(const bf16x8*)(bp);        // ks=0
            const bf16x8 b1 = *(const bf16x8*)(bp + 32);   // ks=1
            acc[ct] = __builtin_amdgcn_mfma_f32_16x16x32_bf16(a0, b0, acc[ct], 0, 0, 0);
            acc[ct] = __builtin_amdgcn_mfma_f32_16x16x32_bf16(a1, b1, acc[ct], 0, 0, 0);
        }
    }
#undef LOADA

    // epilogue: D[row = l4*4+reg][col = l15]
#pragma unroll
    for (int ct = 0; ct < 8; ++ct)
#pragma unroll
        for (int reg = 0; reg < 4; ++reg) {
            const int row = m0 + mw + l4 * 4 + reg;
            if (row < NN)
                h[(size_t)row * DO + ct * 16 + l15] = f2bf(acc[ct][reg]);
        }
}

// ---------------- partition: edges -> fixed-slot bucket lists ---------------
// csr[b*CAP + i]; global bcnt is both cursor and final per-bucket count.
__global__ __launch_bounds__(256)
void part_kernel(const int* __restrict__ erow, const int* __restrict__ ecol,
                 const float* __restrict__ ew, int* __restrict__ bcnt,
                 int2* __restrict__ csr) {
    __shared__ int cnt[NBK];
    __shared__ int base[NBK];
    const int t  = threadIdx.x;
    const int e0 = blockIdx.x * TILE;
    for (int k = t; k < NBK; k += 256) cnt[k] = 0;
    __syncthreads();
    for (int k = 0; k < TILE; k += 256) {
        const int e = e0 + k + t;
        if (e < NE) atomicAdd(&cnt[erow[e] >> 7], 1);
    }
    __syncthreads();
    for (int k = t; k < NBK; k += 256) {
        const int c = cnt[k];
        base[k] = c ? atomicAdd(&bcnt[k], c) : 0;
        cnt[k] = 0;
    }
    __syncthreads();
    for (int k = 0; k < TILE; k += 256) {
        const int e = e0 + k + t;
        if (e < NE) {
            const int row = erow[e];
            const int bk  = row >> 7;
            const int pos = atomicAdd(&cnt[bk], 1);
            int2 v;
            v.x = ((row & 127) << 17) | ecol[e];   // col < 2^17
            v.y = __float_as_int(ew[e]);
            csr[(size_t)bk * CAP + base[bk] + pos] = v;
        }
    }
}

// ---------------- bucket gather: LDS counting sort + register gather --------
// 512 threads/block (grid fixed at 782 -> 3 blocks/CU; wider block = more
// resident waves for latency hiding on random h reads).
__global__ __launch_bounds__(512)
void bgather_kernel(const unsigned short* __restrict__ h,
                    const int* __restrict__ bcnt,
                    const int2* __restrict__ csr, float* __restrict__ out) {
    __shared__ int2 se[CAP];            // sorted edges
    __shared__ int  s_cnt[BROWS];       // histogram -> cursor
    __shared__ int  s_start[BROWS + 1];
    __shared__ int  wtot;
    const int b = blockIdx.x, t = threadIdx.x;
    const int n = bcnt[b];
    const int2* ebase = csr + (size_t)b * CAP;

    if (t < BROWS) s_cnt[t] = 0;
    __syncthreads();
    // pass 1: histogram by row-offset
    for (int j = t; j < n; j += 512)
        atomicAdd(&s_cnt[((unsigned)ebase[j].x) >> 17], 1);
    __syncthreads();
    // scan 128 bins
    const int lane = t & 63;
    int c = 0;
    if (t < BROWS) c = s_cnt[t];
    int v = c;
#pragma unroll
    for (int off = 1; off < 64; off <<= 1) {
        const int nn = __shfl_up(v, off, 64);
        if (lane >= off) v += nn;
    }
    if (t == 63) wtot = v;
    __syncthreads();
    if (t < BROWS) {
        const int excl = v - c + (t >= 64 ? wtot : 0);
        s_start[t] = excl;
        s_cnt[t]   = excl;   // reuse as scatter cursor
    }
    if (t == 0) s_start[BROWS] = n;
    __syncthreads();
    // pass 2: scatter into row-sorted order
    for (int j = t; j < n; j += 512) {
        const int2 cw  = ebase[j];
        const int  pos = atomicAdd(&s_cnt[((unsigned)cw.x) >> 17], 1);
        se[pos] = cw;
    }
    __syncthreads();

    // gather: 32 groups of 16 lanes; group g handles rows g, g+32, g+64, g+96
    const int l16 = t & 15, g = t >> 4;
    const int row0 = b * BROWS;
#pragma unroll
    for (int rp = 0; rp < 4; ++rp) {
        const int r  = rp * 32 + g;
        const int gr = row0 + r;
        const int rs = s_start[r], re = s_start[r + 1];
        float acc[8];
#pragma unroll
        for (int i = 0; i < 8; ++i) acc[i] = 0.f;
        int j = rs;
        for (; j + 2 <= re; j += 2) {
            const int2 cw0 = se[j], cw1 = se[j + 1];
            const float w0 = __int_as_float(cw0.y);
            const float w1 = __int_as_float(cw1.y);
            const uint4 q0 = *(const uint4*)(h + (size_t)(cw0.x & 0x1FFFF) * DO + l16 * 8);
            const uint4 q1 = *(const uint4*)(h + (size_t)(cw1.x & 0x1FFFF) * DO + l16 * 8);
            const unsigned* u0 = (const unsigned*)&q0;
            const unsigned* u1 = (const unsigned*)&q1;
#pragma unroll
            for (int i = 0; i < 4; ++i) {
                acc[2 * i + 0] += w0 * bf2f(u0[i] & 0xFFFF) + w1 * bf2f(u1[i] & 0xFFFF);
                acc[2 * i + 1] += w0 * bf2f(u0[i] >> 16)    + w1 * bf2f(u1[i] >> 16);
            }
        }
        if (j < re) {
            const int2 cw = se[j];
            const float w = __int_as_float(cw.y);
            const uint4 q = *(const uint4*)(h + (size_t)(cw.x & 0x1FFFF) * DO + l16 * 8);
            const unsigned* u = (const unsigned*)&q;
#pragma unroll
            for (int i = 0; i < 4; ++i) {
                acc[2 * i + 0] += w * bf2f(u[i] & 0xFFFF);
                acc[2 * i + 1] += w * bf2f(u[i] >> 16);
            }
        }
        if (gr < NN) {
            float* op = out + (size_t)gr * DO + l16 * 8;
            *(float4*)(op + 0) = make_float4(fmaxf(acc[0], 0.f), fmaxf(acc[1], 0.f),
                                             fmaxf(acc[2], 0.f), fmaxf(acc[3], 0.f));
            *(float4*)(op + 4) = make_float4(fmaxf(acc[4], 0.f), fmaxf(acc[5], 0.f),
                                             fmaxf(acc[6], 0.f), fmaxf(acc[7], 0.f));
        }
    }
}

extern "C" void kernel_launch(void* const* d_in, const int* in_sizes, int n_in,
                              void* d_out, int out_size, void* d_ws, size_t ws_size,
                              hipStream_t stream) {
    const float* x    = (const float*)d_in[0];
    const float* mask = (const float*)d_in[1];
    const float* W    = (const float*)d_in[2];
    const int*   erow = (const int*)d_in[3];
    const int*   ecol = (const int*)d_in[4];
    const float* ew   = (const float*)d_in[5];
    float* out = (float*)d_out;

    char* p = (char*)d_ws;
    unsigned short* h  = (unsigned short*)p;  p += (size_t)NN * DO * 2;   // 25.6 MB
    unsigned short* Wt = (unsigned short*)p;  p += (size_t)DO * DI * 2;   // 64 KB
    int* bcnt = (int*)p;                      p += 3200;
    int2* csr = (int2*)p;                     // NBK*CAP*8 = 16.8 MB

    hipMemsetAsync(bcnt, 0, NBK * sizeof(int), stream);

    wt_kernel<<<32, 256, 0, stream>>>(W, Wt);
    gemm_kernel<<<(NN + 63) / 64, 256, 0, stream>>>(x, mask, Wt, h);
    part_kernel<<<(NE + TILE - 1) / TILE, 256, 0, stream>>>(erow, ecol, ew,
                                                            bcnt, csr);
    bgather_kernel<<<NBK, 512, 0, stream>>>(h, bcnt, csr, out);
}